// Round 12
// baseline (234.383 us; speedup 1.0000x reference)
//
#include <hip/hip_runtime.h>
#include <cstddef>
#include <cstdint>

#define Lq 2048
#define Bq 8
#define Dq 1024
#define Mq (Lq*Bq)   // 16384 rows

typedef _Float16 f16;
typedef _Float16 f16x2 __attribute__((ext_vector_type(2)));
typedef _Float16 f16x8 __attribute__((ext_vector_type(8)));
typedef float f32x4 __attribute__((ext_vector_type(4)));

typedef const __attribute__((address_space(1))) uint32_t GU32;
typedef __attribute__((address_space(3))) uint32_t LU32;

#define BAR()    asm volatile("s_barrier" ::: "memory")
#define WAITV6() asm volatile("s_waitcnt vmcnt(6)" ::: "memory")

// ---------------- fused weight-cvt + token-shift prep ----------------
// Blocks 0..1535: cvt3 (w16[s]=Wr,Wv,Wk -> f16). Blocks 1536..3583: prep.
__global__ __launch_bounds__(256) void prep_k(const float* __restrict__ x,
                                              const float* __restrict__ muk,
                                              const float* __restrict__ muv,
                                              const float* __restrict__ mur,
                                              const float* __restrict__ Wr,
                                              const float* __restrict__ Wv,
                                              const float* __restrict__ Wk,
                                              f16* __restrict__ xk,
                                              f16* __restrict__ xv,
                                              f16* __restrict__ xr,
                                              f16* __restrict__ w16) {
  const int bid = blockIdx.x;
  if (bid < 1536) {
    int y = bid >> 9;                 // 0=Wr, 1=Wv, 2=Wk
    int i = ((bid & 511) * 256 + threadIdx.x) * 8;
    const float* s = (y == 0) ? Wr : (y == 1) ? Wv : Wk;
    f16* d = w16 + (size_t)y * ((size_t)Dq * Dq) + i;
    float4 v0 = *(const float4*)(s + i);
    float4 v1 = *(const float4*)(s + i + 4);
    f16x8 o;
    o[0] = (f16)v0.x; o[1] = (f16)v0.y; o[2] = (f16)v0.z; o[3] = (f16)v0.w;
    o[4] = (f16)v1.x; o[5] = (f16)v1.y; o[6] = (f16)v1.z; o[7] = (f16)v1.w;
    *(f16x8*)d = o;
    return;
  }
  const size_t base0 = ((size_t)(bid - 1536) * 256 + threadIdx.x) * 8;
  const int col = (int)(base0 & (Dq - 1));

  float mk[8], mv[8], mr[8];
#define LD8(MU, DST)                                                           \
  { float4 m0 = *(const float4*)((MU) + col);                                  \
    float4 m1 = *(const float4*)((MU) + col + 4);                              \
    DST[0]=m0.x; DST[1]=m0.y; DST[2]=m0.z; DST[3]=m0.w;                        \
    DST[4]=m1.x; DST[5]=m1.y; DST[6]=m1.z; DST[7]=m1.w; }
  LD8(muk, mk) LD8(muv, mv) LD8(mur, mr)
#undef LD8

#pragma unroll
  for (int it = 0; it < 4; ++it) {
    size_t i = base0 + (size_t)it * 4194304u;
    float4 a0 = *(const float4*)(x + i);
    float4 a1 = *(const float4*)(x + i + 4);
    float4 p0 = make_float4(0.f, 0.f, 0.f, 0.f), p1 = p0;
    if (i >= (size_t)(Bq * Dq)) {
      p0 = *(const float4*)(x + i - Bq * Dq);
      p1 = *(const float4*)(x + i - Bq * Dq + 4);
    }
    float av[8] = {a0.x, a0.y, a0.z, a0.w, a1.x, a1.y, a1.z, a1.w};
    float pv[8] = {p0.x, p0.y, p0.z, p0.w, p1.x, p1.y, p1.z, p1.w};
#define MIX8(MV, DST)                                                          \
    { f16x8 o;                                                                 \
      _Pragma("unroll")                                                        \
      for (int j = 0; j < 8; ++j) o[j] = (f16)(pv[j] + MV[j] * (av[j] - pv[j]));\
      *(f16x8*)((DST) + i) = o; }
    MIX8(mk, xk)
    MIX8(mv, xv)
    MIX8(mr, xr)
#undef MIX8
  }
}

// ---------------- 4-wave 128x256 BK=32 2-slot GEMM core -------------------
// TWO blocks per CU = two independent barrier domains: one block's ds-read
// phase overlaps the other's MFMA phase (m114 TLP). Budget: acc 32xf32x4 =
// 128 AGPR + af[8](32) + bf[4](16) + addr ~40 => ~220 <= 256 at (256,2).
// LDS: As[2][128][32] + Bs[2][256][32] = 48 KB (2 blocks = 96 KB).
//
// Slot liveness (R10/R11-gemmO-verified 2-slot argument): at TILE(q,t),
// slot q^1's tile t-1 reads finished before t-1's trailing BAR; stage t+1
// into q^1 after that BAR. vmcnt: 6 gloads/wave/stage; outstanding after
// stage = 12 -> vmcnt(6) completes own t-loads; BAR makes all waves'
// t-loads visible. Tail restages tile 31 into the free slot (never read;
// keeps the per-wave count invariant exact).
// Swizzle (R9/R10/R11-verified): read col slot = fg ^ ((fr>>1)&3) (2-way
// aliasing = free); linear gload dest + pre-permuted global source col
// s_c = ((lane&3) ^ ((lane>>3)&3))*8 — same involution both sides.
template<int OUTF32>
__device__ __forceinline__ void gemm_core4(const f16* __restrict__ A,
                                           const f16* __restrict__ W,
                                           void* __restrict__ Cv,
                                           int bx, int by) {
  __shared__ f16 As[2][128][32];
  __shared__ f16 Bs[2][256][32];
  const int tid  = threadIdx.x;
  const int lane = tid & 63;
  const int wid  = tid >> 6;           // 0..3 = N-quarter (wc)

  const int fr = lane & 15;
  const int fg = lane >> 4;
  const int cA = (fg ^ ((fr >> 1) & 3)) * 8;   // swizzled f16 col

  // staging: per gload_lds 64 lanes x 16B = 16 rows (4 lanes/row), LDS linear.
  const int s_rA = wid * 32 + (lane >> 2);                  // A rows: 4 waves x 32
  const int s_rB = wid * 64 + (lane >> 2);                  // B rows: 4 waves x 64
  const int s_c  = ((lane & 3) ^ ((lane >> 3) & 3)) * 8;    // f16 units
  const f16* Ag = A + ((size_t)(by * 128 + s_rA)) * Dq + s_c;
  const f16* Wg = W + ((size_t)(bx * 256 + s_rB)) * Dq + s_c;

#define STAGE(slot, kt) do {                                                   \
    __builtin_amdgcn_global_load_lds((GU32*)(Ag + (kt) * 32),                  \
        (LU32*)&As[slot][wid * 32][0], 16, 0, 0);                              \
    __builtin_amdgcn_global_load_lds((GU32*)(Ag + (size_t)16 * Dq + (kt) * 32),\
        (LU32*)&As[slot][wid * 32 + 16][0], 16, 0, 0);                         \
    __builtin_amdgcn_global_load_lds((GU32*)(Wg + (kt) * 32),                  \
        (LU32*)&Bs[slot][wid * 64][0], 16, 0, 0);                              \
    __builtin_amdgcn_global_load_lds((GU32*)(Wg + (size_t)16 * Dq + (kt) * 32),\
        (LU32*)&Bs[slot][wid * 64 + 16][0], 16, 0, 0);                         \
    __builtin_amdgcn_global_load_lds((GU32*)(Wg + (size_t)32 * Dq + (kt) * 32),\
        (LU32*)&Bs[slot][wid * 64 + 32][0], 16, 0, 0);                         \
    __builtin_amdgcn_global_load_lds((GU32*)(Wg + (size_t)48 * Dq + (kt) * 32),\
        (LU32*)&Bs[slot][wid * 64 + 48][0], 16, 0, 0);                         \
  } while (0)

  f16x8 af[8], bf[4];
  f32x4 acc[8][4] = {};

#define TILE(q, t) do {                                                        \
    int st = (t) + 1; if (st > 31) st = 31;                                    \
    STAGE((q) ^ 1, st);                                                        \
    WAITV6();                                                                  \
    BAR();                                                                     \
    _Pragma("unroll")                                                          \
    for (int mi = 0; mi < 8; ++mi)                                             \
      af[mi] = *(const f16x8*)&As[q][mi * 16 + fr][cA];                        \
    _Pragma("unroll")                                                          \
    for (int ni = 0; ni < 4; ++ni)                                             \
      bf[ni] = *(const f16x8*)&Bs[q][wid * 64 + ni * 16 + fr][cA];             \
    __builtin_amdgcn_s_setprio(1);                                             \
    _Pragma("unroll")                                                          \
    for (int mi = 0; mi < 8; ++mi)                                             \
      _Pragma("unroll")                                                        \
      for (int ni = 0; ni < 4; ++ni)                                           \
        acc[mi][ni] = __builtin_amdgcn_mfma_f32_16x16x32_f16(af[mi], bf[ni],   \
                          acc[mi][ni], 0, 0, 0);                               \
    __builtin_amdgcn_s_setprio(0);                                             \
    BAR();                                                                     \
  } while (0)

  STAGE(0, 0);
  for (int tt = 0; tt < 16; ++tt) {
    TILE(0, 2 * tt);
    TILE(1, 2 * tt + 1);
  }

  // Epilogue: C/D layout col=lane&15, row=(lane>>4)*4+reg (m89-verified)
#pragma unroll
  for (int mi = 0; mi < 8; ++mi) {
    const int row0 = by * 128 + mi * 16 + fg * 4;
#pragma unroll
    for (int ni = 0; ni < 4; ++ni) {
      const int col = bx * 256 + wid * 64 + ni * 16 + fr;
      if (OUTF32) {
        float* C = (float*)Cv;
#pragma unroll
        for (int j = 0; j < 4; ++j)
          C[(size_t)(row0 + j) * Dq + col] = acc[mi][ni][j];
      } else {
        f16* C = (f16*)Cv;
#pragma unroll
        for (int j = 0; j < 4; ++j)
          C[(size_t)(row0 + j) * Dq + col] = (f16)acc[mi][ni][j];
      }
    }
  }
#undef STAGE
#undef TILE
}

// 3-stream GEMM: 1536 blocks (512/stream: 4 N-tiles x 128 M-tiles), 2/CU.
// s = bid>>9 (0=r, 1=v, 2=k; k/v last -> L3-warm for scan).
__global__ __launch_bounds__(256, 2) void gemm3_k(const f16* __restrict__ xr,
                                                  const f16* __restrict__ xv,
                                                  const f16* __restrict__ xk,
                                                  const f16* __restrict__ w16,
                                                  f16* __restrict__ rb,
                                                  f16* __restrict__ vb,
                                                  f16* __restrict__ kb) {
  const int s = blockIdx.x >> 9;
  const int inner = blockIdx.x & 511;
  const int wg = (inner & 7) * 64 + (inner >> 3);   // XCD swizzle (512%8==0)
  const f16* A = (s == 0) ? xr : (s == 1) ? xv : xk;
  const f16* W = w16 + (size_t)s * Dq * Dq;
  f16* C = (s == 0) ? rb : (s == 1) ? vb : kb;
  gemm_core4<0>(A, W, C, wg & 3, wg >> 2);
}

// Output GEMM: 512 blocks, f32 out.
__global__ __launch_bounds__(256, 2) void gemmO_k(const f16* __restrict__ A,
                                                  const f16* __restrict__ W,
                                                  float* __restrict__ C) {
  const int wg = (blockIdx.x & 7) * 64 + (blockIdx.x >> 3);
  gemm_core4<1>(A, W, C, wg & 3, wg >> 2);
}

// ---------------- fused WKV scan + Wo cvt ----------------
// Blocks 0..1023: scan (CHUNK=32, LB=16). Blocks 1024..1535: cvt1 Wo->wo16.
// decay = exp(-exp(w)) <= e^-1; LB=16 worst-case tail ~3e-4 rel.
// y aliases rr (read-then-write same index, disjoint chunks).
constexpr int CHUNK = 32, LOOKBACK = 16;

__global__ __launch_bounds__(256) void scan_k(const f16* __restrict__ kk,
                                              const f16* __restrict__ vv,
                                              const f16* rr,
                                              const float* __restrict__ w,
                                              const float* __restrict__ u,
                                              f16* y,
                                              const float* __restrict__ Wo,
                                              f16* __restrict__ wo16) {
  const int bid = blockIdx.x;
  if (bid >= 1024) {
    int i = ((bid - 1024) * 256 + threadIdx.x) * 8;
    float4 v0 = *(const float4*)(Wo + i);
    float4 v1 = *(const float4*)(Wo + i + 4);
    f16x8 o;
    o[0] = (f16)v0.x; o[1] = (f16)v0.y; o[2] = (f16)v0.z; o[3] = (f16)v0.w;
    o[4] = (f16)v1.x; o[5] = (f16)v1.y; o[6] = (f16)v1.z; o[7] = (f16)v1.w;
    *(f16x8*)(wo16 + i) = o;
    return;
  }
  const int unit = (bid >> 6) * 256 + threadIdx.x;   // 0..4095 = (b, d-pair)
  const int d = (unit & 511) * 2;
  const int b = unit >> 9;
  const int t0 = (bid & 63) * CHUNK;

  const float dec0 = __expf(-__expf(w[d]));
  const float dec1 = __expf(-__expf(w[d + 1]));
  const float eu0  = __expf(u[d]);
  const float eu1  = __expf(u[d + 1]);

  float A0 = 0.f, A1 = 0.f, Av0 = 0.f, Av1 = 0.f;
  const size_t base = (size_t)b * Dq + d;

  if (t0 > 0) {
#pragma unroll
    for (int t = t0 - LOOKBACK; t < t0; ++t) {
      size_t idx = (size_t)t * (Bq * Dq) + base;
      f16x2 k2 = *(const f16x2*)(kk + idx);
      f16x2 v2 = *(const f16x2*)(vv + idx);
      float ek0 = __expf((float)k2[0]), ek1 = __expf((float)k2[1]);
      A0  = fmaf(dec0, A0,  ek0);
      A1  = fmaf(dec1, A1,  ek1);
      Av0 = fmaf(dec0, Av0, ek0 * (float)v2[0]);
      Av1 = fmaf(dec1, Av1, ek1 * (float)v2[1]);
    }
  }
#pragma unroll
  for (int t = t0; t < t0 + CHUNK; ++t) {
    size_t idx = (size_t)t * (Bq * Dq) + base;
    f16x2 k2 = *(const f16x2*)(kk + idx);
    f16x2 v2 = *(const f16x2*)(vv + idx);
    f16x2 r2 = *(const f16x2*)(rr + idx);
    float ek0 = __expf((float)k2[0]), ek1 = __expf((float)k2[1]);
    float ekv0 = ek0 * (float)v2[0], ekv1 = ek1 * (float)v2[1];
    float den0 = fmaf(ek0,  eu0, A0),  den1 = fmaf(ek1,  eu1, A1);
    float num0 = fmaf(ekv0, eu0, Av0), num1 = fmaf(ekv1, eu1, Av1);
    float s0 = __builtin_amdgcn_rcpf(1.f + __expf(-(float)r2[0]));
    float s1 = __builtin_amdgcn_rcpf(1.f + __expf(-(float)r2[1]));
    f16x2 o;
    o[0] = (f16)(s0 * num0 * __builtin_amdgcn_rcpf(den0));
    o[1] = (f16)(s1 * num1 * __builtin_amdgcn_rcpf(den1));
    *(f16x2*)(y + idx) = o;
    A0  = fmaf(dec0, A0,  ek0);
    A1  = fmaf(dec1, A1,  ek1);
    Av0 = fmaf(dec0, Av0, ekv0);
    Av1 = fmaf(dec1, Av1, ekv1);
  }
}

extern "C" void kernel_launch(void* const* d_in, const int* in_sizes, int n_in,
                              void* d_out, int out_size, void* d_ws, size_t ws_size,
                              hipStream_t stream) {
  const float* x    = (const float*)d_in[0];
  const float* mu_k = (const float*)d_in[1];
  const float* mu_v = (const float*)d_in[2];
  const float* mu_r = (const float*)d_in[3];
  const float* Wk   = (const float*)d_in[4];
  const float* Wv   = (const float*)d_in[5];
  const float* Wr   = (const float*)d_in[6];
  const float* Wo   = (const float*)d_in[7];
  const float* w    = (const float*)d_in[8];
  const float* u    = (const float*)d_in[9];

  // Workspace (192 MB):
  f16* xk = (f16*)d_ws;                    // 32 MB each
  f16* xv = xk + (size_t)Mq * Dq;
  f16* xr = xv + (size_t)Mq * Dq;
  f16* kb = xr + (size_t)Mq * Dq;
  f16* vb = kb + (size_t)Mq * Dq;
  f16* rb = vb + (size_t)Mq * Dq;
  // w16 (Wr|Wv|Wk, 6MB) lives in d_out, overwritten by final GEMM.
  // wo16 reuses xv region — dead after gemm3_k; cvt runs inside scan launch.
  f16* w16  = (f16*)d_out;
  f16* wo16 = xv;

  prep_k<<<3584, 256, 0, stream>>>(x, mu_k, mu_v, mu_r, Wr, Wv, Wk,
                                   xk, xv, xr, w16);
  gemm3_k<<<1536, 256, 0, stream>>>(xr, xv, xk, w16, rb, vb, kb);
  scan_k<<<1536, 256, 0, stream>>>(kb, vb, rb, w, u, rb, Wo, wo16);
  gemmO_k<<<512, 256, 0, stream>>>(rb, wo16, (float*)d_out);
}